// Round 1
// baseline (531.831 us; speedup 1.0000x reference)
//
#include <hip/hip_runtime.h>

#define DIM 128

// ---------------- init: zero out, zero degrees, map=-1 ----------------
__global__ void k_init(float* __restrict__ out, float* __restrict__ deg_o,
                       float* __restrict__ deg_i, int* __restrict__ map, int n_fine) {
    size_t stride = (size_t)gridDim.x * blockDim.x;
    size_t tid = (size_t)blockIdx.x * blockDim.x + threadIdx.x;
    size_t tot4 = (size_t)n_fine * DIM / 4;
    float4* o4 = (float4*)out;
    const float4 z = make_float4(0.f, 0.f, 0.f, 0.f);
    for (size_t i = tid; i < tot4; i += stride) o4[i] = z;
    for (size_t i = tid; i < (size_t)n_fine; i += stride) {
        deg_o[i] = 0.f;
        deg_i[i] = 0.f;
        map[i] = -1;
    }
}

// ---------------- degrees (atomic histogram) + select map ----------------
__global__ void k_deg_map(const int* __restrict__ src, const int* __restrict__ dst,
                          float* __restrict__ deg_o, float* __restrict__ deg_i,
                          const int* __restrict__ sel, int* __restrict__ map,
                          int n_edges, int n_sel) {
    int stride = gridDim.x * blockDim.x;
    int tid = blockIdx.x * blockDim.x + threadIdx.x;
    for (int e = tid; e < n_edges; e += stride) {
        atomicAdd(&deg_o[src[e]], 1.f);
        atomicAdd(&deg_i[dst[e]], 1.f);
    }
    for (int i = tid; i < n_sel; i += stride) map[sel[i]] = i;
}

// ---------------- deg -> rsqrt(max(deg,1)) in place ----------------
__global__ void k_inv(float* __restrict__ deg_o, float* __restrict__ deg_i, int n) {
    int stride = gridDim.x * blockDim.x;
    int tid = blockIdx.x * blockDim.x + threadIdx.x;
    for (int i = tid; i < n; i += stride) {
        deg_o[i] = rsqrtf(fmaxf(deg_o[i], 1.f));
        deg_i[i] = rsqrtf(fmaxf(deg_i[i], 1.f));
    }
}

// ---------------- hw[c] = (feat[c] @ W) * deg_o_inv[sel[c]] ----------------
// One 128-thread block; W staged in LDS (exactly 64 KiB). Thread t owns column t.
// Wl[k*128+t]: bank = t%32 -> 2-way alias across 64 lanes (free). x-row loads are
// wave-uniform float4 -> L1 broadcast.
__global__ __launch_bounds__(128) void k_gemm(
    const float* __restrict__ feat, const int* __restrict__ sel,
    const float* __restrict__ deg_o_inv, const float* __restrict__ W,
    float* __restrict__ hw, int n_coarse) {
    __shared__ float Wl[DIM * DIM];
    int t = threadIdx.x;
    for (int i = t; i < DIM * DIM; i += 128) Wl[i] = W[i];
    __syncthreads();
    for (int r = blockIdx.x; r < n_coarse; r += gridDim.x) {
        float sc = deg_o_inv[sel[r]];
        const float4* xr = (const float4*)(feat + (size_t)r * DIM);
        float acc = 0.f;
#pragma unroll
        for (int k4 = 0; k4 < DIM / 4; ++k4) {
            float4 xv = xr[k4];
            acc += xv.x * Wl[(k4 * 4 + 0) * DIM + t];
            acc += xv.y * Wl[(k4 * 4 + 1) * DIM + t];
            acc += xv.z * Wl[(k4 * 4 + 2) * DIM + t];
            acc += xv.w * Wl[(k4 * 4 + 3) * DIM + t];
        }
        hw[(size_t)r * DIM + t] = acc * sc;  // (x*sc)@W == sc*(x@W)
    }
}

// ---------------- edge scatter: out[dst] += hw[map[src]] ----------------
// One wave (64 lanes) per edge; lane handles 2 columns. Edges whose src is not
// a selected node contribute zero -> skipped (~50%).
__global__ void k_edge(const int* __restrict__ src, const int* __restrict__ dst,
                       const int* __restrict__ map, const float* __restrict__ hw,
                       float* __restrict__ out, int n_edges) {
    int gid = blockIdx.x * blockDim.x + threadIdx.x;
    int lane = gid & 63;
    int wave = gid >> 6;
    int nwaves = (gridDim.x * blockDim.x) >> 6;
    for (int e = wave; e < n_edges; e += nwaves) {
        int c = map[src[e]];
        if (c < 0) continue;
        const float2 v = *(const float2*)(hw + (size_t)c * DIM + lane * 2);
        float* o = out + (size_t)dst[e] * DIM + lane * 2;
        atomicAdd(o, v.x);
        atomicAdd(o + 1, v.y);
    }
}

// ---------------- out = out * deg_i_inv[row] + bias[col] ----------------
__global__ void k_final(float* __restrict__ out, const float* __restrict__ deg_i_inv,
                        const float* __restrict__ bias, int n_fine) {
    size_t tid = (size_t)blockIdx.x * blockDim.x + threadIdx.x;
    size_t stride = (size_t)gridDim.x * blockDim.x;
    size_t tot4 = (size_t)n_fine * DIM / 4;
    float4* o4 = (float4*)out;
    const float4* b4 = (const float4*)bias;
    for (size_t i = tid; i < tot4; i += stride) {
        int row = (int)(i >> 5);  // 32 float4 per row
        int c4 = (int)(i & 31);
        float s = deg_i_inv[row];
        float4 v = o4[i];
        float4 b = b4[c4];
        v.x = v.x * s + b.x;
        v.y = v.y * s + b.y;
        v.z = v.z * s + b.z;
        v.w = v.w * s + b.w;
        o4[i] = v;
    }
}

extern "C" void kernel_launch(void* const* d_in, const int* in_sizes, int n_in,
                              void* d_out, int out_size, void* d_ws, size_t ws_size,
                              hipStream_t stream) {
    const float* feat = (const float*)d_in[0];
    const int* src = (const int*)d_in[1];
    const int* dst = (const int*)d_in[2];
    const int* sel = (const int*)d_in[3];
    const float* W = (const float*)d_in[4];
    const float* bias = (const float*)d_in[5];
    float* out = (float*)d_out;

    int n_fine = out_size / DIM;       // 50000
    int n_coarse = in_sizes[0] / DIM;  // 25000
    int n_edges = in_sizes[1];         // 800000

    // Workspace layout (all 4-byte aligned):
    //   deg_o [n_fine] f32 | deg_i [n_fine] f32 | map [n_fine] i32 | hw [n_coarse*128] f32
    float* deg_o = (float*)d_ws;
    float* deg_i = deg_o + n_fine;
    int* map = (int*)(deg_i + n_fine);
    float* hw = (float*)(map + n_fine);

    hipLaunchKernelGGL(k_init, dim3(2048), dim3(256), 0, stream, out, deg_o, deg_i, map, n_fine);
    hipLaunchKernelGGL(k_deg_map, dim3(1024), dim3(256), 0, stream, src, dst, deg_o, deg_i,
                       sel, map, n_edges, n_coarse);
    hipLaunchKernelGGL(k_inv, dim3(256), dim3(256), 0, stream, deg_o, deg_i, n_fine);
    hipLaunchKernelGGL(k_gemm, dim3(1024), dim3(128), 0, stream, feat, sel, deg_o, W, hw, n_coarse);
    hipLaunchKernelGGL(k_edge, dim3(2048), dim3(256), 0, stream, src, dst, map, hw, out, n_edges);
    hipLaunchKernelGGL(k_final, dim3(2048), dim3(256), 0, stream, out, deg_i, bias, n_fine);
}

// Round 2
// 216.355 us; speedup vs baseline: 2.4581x; 2.4581x over previous
//
#include <hip/hip_runtime.h>

#define DIM 128

// ---------------- setup: zero counters, map=-1 ----------------
__global__ void k_setup(int* __restrict__ deg_o, int* __restrict__ deg_i,
                        int* __restrict__ cursor, int* __restrict__ map, int n_fine) {
    int stride = gridDim.x * blockDim.x;
    int tid = blockIdx.x * blockDim.x + threadIdx.x;
    for (int i = tid; i < n_fine; i += stride) {
        deg_o[i] = 0;
        deg_i[i] = 0;
        cursor[i] = 0;
        map[i] = -1;
    }
}

// ---------------- map[sel[i]] = i ----------------
__global__ void k_map(const int* __restrict__ sel, int* __restrict__ map, int n_sel) {
    int tid = blockIdx.x * blockDim.x + threadIdx.x;
    if (tid < n_sel) map[sel[tid]] = tid;
}

// ---------------- degree histograms (int atomics) ----------------
__global__ void k_deg(const int* __restrict__ src, const int* __restrict__ dst,
                      int* __restrict__ deg_o, int* __restrict__ deg_i, int n_edges) {
    int stride = gridDim.x * blockDim.x;
    int tid = blockIdx.x * blockDim.x + threadIdx.x;
    for (int e = tid; e < n_edges; e += stride) {
        atomicAdd(&deg_o[src[e]], 1);
        atomicAdd(&deg_i[dst[e]], 1);
    }
}

// ---------------- exclusive scan of deg_i -> off (3 tiny kernels) ----------------
__global__ __launch_bounds__(256) void k_scan1(const int* __restrict__ deg,
                                               int* __restrict__ off,
                                               int* __restrict__ blksum, int n) {
    __shared__ int s[256];
    int t = threadIdx.x;
    int base = blockIdx.x * 1024 + t * 4;
    int v0 = 0, v1 = 0, v2 = 0, v3 = 0;
    if (base + 3 < n) {
        int4 q = *(const int4*)(deg + base);
        v0 = q.x; v1 = q.y; v2 = q.z; v3 = q.w;
    } else {
        if (base + 0 < n) v0 = deg[base + 0];
        if (base + 1 < n) v1 = deg[base + 1];
        if (base + 2 < n) v2 = deg[base + 2];
    }
    int sum = v0 + v1 + v2 + v3;
    s[t] = sum;
    __syncthreads();
    for (int d = 1; d < 256; d <<= 1) {
        int x = (t >= d) ? s[t - d] : 0;
        __syncthreads();
        if (t >= d) s[t] += x;
        __syncthreads();
    }
    int excl = s[t] - sum;
    if (t == 255) blksum[blockIdx.x] = s[255];
    if (base + 0 < n) off[base + 0] = excl;
    if (base + 1 < n) off[base + 1] = excl + v0;
    if (base + 2 < n) off[base + 2] = excl + v0 + v1;
    if (base + 3 < n) off[base + 3] = excl + v0 + v1 + v2;
}

__global__ void k_scan2(int* __restrict__ blksum, int nb) {
    if (threadIdx.x == 0 && blockIdx.x == 0) {
        int run = 0;
        for (int b = 0; b < nb; ++b) {
            int x = blksum[b];
            blksum[b] = run;
            run += x;
        }
    }
}

__global__ void k_scan3(int* __restrict__ off, const int* __restrict__ blksum, int n) {
    int stride = gridDim.x * blockDim.x;
    int tid = blockIdx.x * blockDim.x + threadIdx.x;
    for (int i = tid; i < n; i += stride) off[i] += blksum[i >> 10];
}

// ---------------- hw[c] = (feat[c] @ W) * rsqrt(max(deg_o[sel[c]],1)) ----------------
// Block = 256 threads: col = t&127, row-group = t>>7 (2 groups x 4 rows = 8 rows/iter).
// W staged once per block in LDS (64 KiB). Each W element read once per 4 rows
// (register-blocked) -> LDS traffic /4 vs naive.
__global__ __launch_bounds__(256) void k_gemm(
    const float* __restrict__ feat, const int* __restrict__ sel,
    const int* __restrict__ deg_o, const float* __restrict__ W,
    float* __restrict__ hw, int n_coarse) {
    __shared__ float Wl[DIM * DIM];
    int t = threadIdx.x;
    for (int i = t; i < DIM * DIM; i += 256) Wl[i] = W[i];
    __syncthreads();
    int col = t & 127;
    int rg = t >> 7;
    for (int base = blockIdx.x * 8; base < n_coarse; base += gridDim.x * 8) {
        int r0 = base + rg * 4;
        float acc0 = 0.f, acc1 = 0.f, acc2 = 0.f, acc3 = 0.f;
        bool full = (r0 + 3 < n_coarse);
        if (full) {
            const float* f0 = feat + (size_t)r0 * DIM;
#pragma unroll
            for (int k4 = 0; k4 < DIM / 4; ++k4) {
                float w0 = Wl[(4 * k4 + 0) * DIM + col];
                float w1 = Wl[(4 * k4 + 1) * DIM + col];
                float w2 = Wl[(4 * k4 + 2) * DIM + col];
                float w3 = Wl[(4 * k4 + 3) * DIM + col];
                float4 x0 = *(const float4*)(f0 + 0 * DIM + k4 * 4);
                float4 x1 = *(const float4*)(f0 + 1 * DIM + k4 * 4);
                float4 x2 = *(const float4*)(f0 + 2 * DIM + k4 * 4);
                float4 x3 = *(const float4*)(f0 + 3 * DIM + k4 * 4);
                acc0 += x0.x * w0 + x0.y * w1 + x0.z * w2 + x0.w * w3;
                acc1 += x1.x * w0 + x1.y * w1 + x1.z * w2 + x1.w * w3;
                acc2 += x2.x * w0 + x2.y * w1 + x2.z * w2 + x2.w * w3;
                acc3 += x3.x * w0 + x3.y * w1 + x3.z * w2 + x3.w * w3;
            }
            float s0 = rsqrtf((float)max(deg_o[sel[r0 + 0]], 1));
            float s1 = rsqrtf((float)max(deg_o[sel[r0 + 1]], 1));
            float s2 = rsqrtf((float)max(deg_o[sel[r0 + 2]], 1));
            float s3 = rsqrtf((float)max(deg_o[sel[r0 + 3]], 1));
            hw[(size_t)(r0 + 0) * DIM + col] = acc0 * s0;
            hw[(size_t)(r0 + 1) * DIM + col] = acc1 * s1;
            hw[(size_t)(r0 + 2) * DIM + col] = acc2 * s2;
            hw[(size_t)(r0 + 3) * DIM + col] = acc3 * s3;
        } else {
            for (int r = r0; r < n_coarse; ++r) {
                float acc = 0.f;
                const float* fr = feat + (size_t)r * DIM;
                for (int k = 0; k < DIM; ++k) acc += fr[k] * Wl[k * DIM + col];
                hw[(size_t)r * DIM + col] = acc * rsqrtf((float)max(deg_o[sel[r]], 1));
            }
        }
    }
}

// ---------------- bucket fill: CSR of active edges per dst ----------------
__global__ void k_bucket(const int* __restrict__ src, const int* __restrict__ dst,
                         const int* __restrict__ map, const int* __restrict__ off,
                         int* __restrict__ cursor, int* __restrict__ bucket, int n_edges) {
    int stride = gridDim.x * blockDim.x;
    int tid = blockIdx.x * blockDim.x + threadIdx.x;
    for (int e = tid; e < n_edges; e += stride) {
        int c = map[src[e]];
        if (c < 0) continue;
        int d = dst[e];
        int p = atomicAdd(&cursor[d], 1);
        bucket[off[d] + p] = c;
    }
}

// ---------------- gather: out[v] = (sum_{e in N(v)} hw[c_e]) * rsqrt(deg_i) + bias ----------------
// One wave per dst node; lane handles 2 columns (float2). Writes each output row once.
__global__ void k_gather(const int* __restrict__ off, const int* __restrict__ cursor,
                         const int* __restrict__ deg_i, const int* __restrict__ bucket,
                         const float* __restrict__ hw, const float* __restrict__ bias,
                         float* __restrict__ out, int n_fine) {
    int gid = blockIdx.x * blockDim.x + threadIdx.x;
    int lane = gid & 63;
    int wave = gid >> 6;
    int nwaves = (gridDim.x * blockDim.x) >> 6;
    float2 b = *(const float2*)(bias + lane * 2);
    for (int v = wave; v < n_fine; v += nwaves) {
        int o = off[v];
        int n = cursor[v];
        float accx = 0.f, accy = 0.f;
        for (int j = 0; j < n; ++j) {
            int c = bucket[o + j];
            float2 x = *(const float2*)(hw + (size_t)c * DIM + lane * 2);
            accx += x.x;
            accy += x.y;
        }
        float s = rsqrtf((float)max(deg_i[v], 1));
        float2 r;
        r.x = accx * s + b.x;
        r.y = accy * s + b.y;
        *(float2*)(out + (size_t)v * DIM + lane * 2) = r;
    }
}

extern "C" void kernel_launch(void* const* d_in, const int* in_sizes, int n_in,
                              void* d_out, int out_size, void* d_ws, size_t ws_size,
                              hipStream_t stream) {
    const float* feat = (const float*)d_in[0];
    const int* src = (const int*)d_in[1];
    const int* dst = (const int*)d_in[2];
    const int* sel = (const int*)d_in[3];
    const float* W = (const float*)d_in[4];
    const float* bias = (const float*)d_in[5];
    float* out = (float*)d_out;

    int n_fine = out_size / DIM;       // 50000
    int n_coarse = in_sizes[0] / DIM;  // 25000
    int n_edges = in_sizes[1];         // 800000

    // Workspace layout (ints then floats, all 16B-aligned for this shape):
    int* deg_o = (int*)d_ws;                 // [n_fine]
    int* deg_i = deg_o + n_fine;             // [n_fine]
    int* map = deg_i + n_fine;               // [n_fine]
    int* off = map + n_fine;                 // [n_fine]
    int* cursor = off + n_fine;              // [n_fine]
    int* blksum = cursor + n_fine;           // [64]
    float* hw = (float*)(blksum + 64);       // [n_coarse*DIM]
    int* bucket = (int*)(hw + (size_t)n_coarse * DIM);  // [n_edges]

    int nb = (n_fine + 1023) / 1024;  // scan blocks (<= 64)

    hipLaunchKernelGGL(k_setup, dim3(256), dim3(256), 0, stream, deg_o, deg_i, cursor, map, n_fine);
    hipLaunchKernelGGL(k_map, dim3((n_coarse + 255) / 256), dim3(256), 0, stream, sel, map, n_coarse);
    hipLaunchKernelGGL(k_deg, dim3(1024), dim3(256), 0, stream, src, dst, deg_o, deg_i, n_edges);
    hipLaunchKernelGGL(k_scan1, dim3(nb), dim3(256), 0, stream, deg_i, off, blksum, n_fine);
    hipLaunchKernelGGL(k_scan2, dim3(1), dim3(64), 0, stream, blksum, nb);
    hipLaunchKernelGGL(k_scan3, dim3(256), dim3(256), 0, stream, off, blksum, n_fine);
    hipLaunchKernelGGL(k_gemm, dim3(512), dim3(256), 0, stream, feat, sel, deg_o, W, hw, n_coarse);
    hipLaunchKernelGGL(k_bucket, dim3(1024), dim3(256), 0, stream, src, dst, map, off, cursor, bucket, n_edges);
    hipLaunchKernelGGL(k_gather, dim3((n_fine * 64 + 255) / 256), dim3(256), 0, stream,
                       off, cursor, deg_i, bucket, hw, bias, out, n_fine);
}

// Round 3
// 152.500 us; speedup vs baseline: 3.4874x; 1.4187x over previous
//
#include <hip/hip_runtime.h>

#define DIM 128
#define NB 64          // edge chunks per histogram
#define HIST_T 512     // threads per hist block

// ---------------- privatized LDS histograms ----------------
// Grid = 4*NB blocks. Decode: b = chunk, g = {h (src|dst) , r (node-range half)}.
// Each block counts its 12500-edge chunk into packed 2xu16 LDS bins covering half
// the node range, then flushes non-atomically to partial[(g*NB+b)*half_words + w].
__global__ __launch_bounds__(HIST_T) void k_hist(
    const int* __restrict__ src, const int* __restrict__ dst,
    unsigned int* __restrict__ partial, int n_edges, int half_words, int chunk) {
    __shared__ unsigned int hist[12512];  // 50 KB; half_words <= 12512
    int b = blockIdx.x & (NB - 1);
    int g = blockIdx.x >> 6;          // 0..3
    int r = g & 1;                    // node-range half
    const int* __restrict__ idx = (g >> 1) ? dst : src;
    int half_bins = half_words * 2;
    int lo = r * half_bins;

    for (int i = threadIdx.x; i < half_words; i += HIST_T) hist[i] = 0;
    __syncthreads();

    int e0 = b * chunk;
    int e1 = min(e0 + chunk, n_edges);
    // e0 is a multiple of 4 when chunk%4==0; int4 fast path + scalar tail.
    int qs = e0 >> 2, qe = e1 >> 2;
    for (int q = qs + threadIdx.x; q < qe; q += HIST_T) {
        int4 v = ((const int4*)idx)[q];
        unsigned int t;
        t = (unsigned int)(v.x - lo);
        if (t < (unsigned int)half_bins) atomicAdd(&hist[t >> 1], 1u << ((t & 1) * 16));
        t = (unsigned int)(v.y - lo);
        if (t < (unsigned int)half_bins) atomicAdd(&hist[t >> 1], 1u << ((t & 1) * 16));
        t = (unsigned int)(v.z - lo);
        if (t < (unsigned int)half_bins) atomicAdd(&hist[t >> 1], 1u << ((t & 1) * 16));
        t = (unsigned int)(v.w - lo);
        if (t < (unsigned int)half_bins) atomicAdd(&hist[t >> 1], 1u << ((t & 1) * 16));
    }
    for (int e = (qe << 2) + threadIdx.x; e < e1; e += HIST_T) {
        unsigned int t = (unsigned int)(idx[e] - lo);
        if (t < (unsigned int)half_bins) atomicAdd(&hist[t >> 1], 1u << ((t & 1) * 16));
    }
    __syncthreads();

    unsigned int* dstp = partial + (size_t)blockIdx.x * half_words;
    for (int i = threadIdx.x; i < half_words; i += HIST_T) dstp[i] = hist[i];
}

// ---------------- reduce partials -> deg_o, deg_i; init map=-1, cursor=0 ----------------
__global__ void k_hreduce(const unsigned int* __restrict__ partial,
                          int* __restrict__ deg_o, int* __restrict__ deg_i,
                          int* __restrict__ map, int* __restrict__ cursor,
                          int half_words, int n_fine) {
    int w = blockIdx.x * blockDim.x + threadIdx.x;  // global word 0..2*half_words
    int words = half_words * 2;
    if (w >= words) return;
    int r = (w >= half_words) ? 1 : 0;
    int wl = w - r * half_words;
    unsigned int s0 = 0, s1 = 0;
    const unsigned int* p0 = partial + (size_t)(r * NB) * half_words + wl;        // h=0 (src)
    const unsigned int* p1 = partial + (size_t)((2 + r) * NB) * half_words + wl;  // h=1 (dst)
    for (int b = 0; b < NB; ++b) {
        s0 += p0[(size_t)b * half_words];
        s1 += p1[(size_t)b * half_words];
    }
    int i0 = 2 * w, i1 = 2 * w + 1;
    if (i0 < n_fine) {
        deg_o[i0] = (int)(s0 & 0xFFFF);
        deg_i[i0] = (int)(s1 & 0xFFFF);
        map[i0] = -1;
        cursor[i0] = 0;
    }
    if (i1 < n_fine) {
        deg_o[i1] = (int)(s0 >> 16);
        deg_i[i1] = (int)(s1 >> 16);
        map[i1] = -1;
        cursor[i1] = 0;
    }
}

// ---------------- map[sel[i]] = i ----------------
__global__ void k_map(const int* __restrict__ sel, int* __restrict__ map, int n_sel) {
    int tid = blockIdx.x * blockDim.x + threadIdx.x;
    if (tid < n_sel) map[sel[tid]] = tid;
}

// ---------------- exclusive scan of deg_i -> off ----------------
__global__ __launch_bounds__(256) void k_scan1(const int* __restrict__ deg,
                                               int* __restrict__ off,
                                               int* __restrict__ blksum, int n) {
    __shared__ int s[256];
    int t = threadIdx.x;
    int base = blockIdx.x * 1024 + t * 4;
    int v0 = 0, v1 = 0, v2 = 0, v3 = 0;
    if (base + 3 < n) {
        int4 q = *(const int4*)(deg + base);
        v0 = q.x; v1 = q.y; v2 = q.z; v3 = q.w;
    } else {
        if (base + 0 < n) v0 = deg[base + 0];
        if (base + 1 < n) v1 = deg[base + 1];
        if (base + 2 < n) v2 = deg[base + 2];
    }
    int sum = v0 + v1 + v2 + v3;
    s[t] = sum;
    __syncthreads();
    for (int d = 1; d < 256; d <<= 1) {
        int x = (t >= d) ? s[t - d] : 0;
        __syncthreads();
        if (t >= d) s[t] += x;
        __syncthreads();
    }
    int excl = s[t] - sum;
    if (t == 255) blksum[blockIdx.x] = s[255];
    if (base + 0 < n) off[base + 0] = excl;
    if (base + 1 < n) off[base + 1] = excl + v0;
    if (base + 2 < n) off[base + 2] = excl + v0 + v1;
    if (base + 3 < n) off[base + 3] = excl + v0 + v1 + v2;
}

__global__ void k_scan2(int* __restrict__ blksum, int nb) {
    if (threadIdx.x == 0 && blockIdx.x == 0) {
        int run = 0;
        for (int b = 0; b < nb; ++b) {
            int x = blksum[b];
            blksum[b] = run;
            run += x;
        }
    }
}

__global__ void k_scan3(int* __restrict__ off, const int* __restrict__ blksum, int n) {
    int stride = gridDim.x * blockDim.x;
    int tid = blockIdx.x * blockDim.x + threadIdx.x;
    for (int i = tid; i < n; i += stride) off[i] += blksum[i >> 10];
}

// ---------------- hw[c] = (feat[c] @ W) * rsqrt(max(deg_o[sel[c]],1)) ----------------
__global__ __launch_bounds__(256) void k_gemm(
    const float* __restrict__ feat, const int* __restrict__ sel,
    const int* __restrict__ deg_o, const float* __restrict__ W,
    float* __restrict__ hw, int n_coarse) {
    __shared__ float Wl[DIM * DIM];
    int t = threadIdx.x;
    for (int i = t; i < DIM * DIM; i += 256) Wl[i] = W[i];
    __syncthreads();
    int col = t & 127;
    int rg = t >> 7;
    for (int base = blockIdx.x * 8; base < n_coarse; base += gridDim.x * 8) {
        int r0 = base + rg * 4;
        float acc0 = 0.f, acc1 = 0.f, acc2 = 0.f, acc3 = 0.f;
        bool full = (r0 + 3 < n_coarse);
        if (full) {
            const float* f0 = feat + (size_t)r0 * DIM;
#pragma unroll
            for (int k4 = 0; k4 < DIM / 4; ++k4) {
                float w0 = Wl[(4 * k4 + 0) * DIM + col];
                float w1 = Wl[(4 * k4 + 1) * DIM + col];
                float w2 = Wl[(4 * k4 + 2) * DIM + col];
                float w3 = Wl[(4 * k4 + 3) * DIM + col];
                float4 x0 = *(const float4*)(f0 + 0 * DIM + k4 * 4);
                float4 x1 = *(const float4*)(f0 + 1 * DIM + k4 * 4);
                float4 x2 = *(const float4*)(f0 + 2 * DIM + k4 * 4);
                float4 x3 = *(const float4*)(f0 + 3 * DIM + k4 * 4);
                acc0 += x0.x * w0 + x0.y * w1 + x0.z * w2 + x0.w * w3;
                acc1 += x1.x * w0 + x1.y * w1 + x1.z * w2 + x1.w * w3;
                acc2 += x2.x * w0 + x2.y * w1 + x2.z * w2 + x2.w * w3;
                acc3 += x3.x * w0 + x3.y * w1 + x3.z * w2 + x3.w * w3;
            }
            float s0 = rsqrtf((float)max(deg_o[sel[r0 + 0]], 1));
            float s1 = rsqrtf((float)max(deg_o[sel[r0 + 1]], 1));
            float s2 = rsqrtf((float)max(deg_o[sel[r0 + 2]], 1));
            float s3 = rsqrtf((float)max(deg_o[sel[r0 + 3]], 1));
            hw[(size_t)(r0 + 0) * DIM + col] = acc0 * s0;
            hw[(size_t)(r0 + 1) * DIM + col] = acc1 * s1;
            hw[(size_t)(r0 + 2) * DIM + col] = acc2 * s2;
            hw[(size_t)(r0 + 3) * DIM + col] = acc3 * s3;
        } else {
            for (int r = r0; r < n_coarse; ++r) {
                float acc = 0.f;
                const float* fr = feat + (size_t)r * DIM;
                for (int k = 0; k < DIM; ++k) acc += fr[k] * Wl[k * DIM + col];
                hw[(size_t)r * DIM + col] = acc * rsqrtf((float)max(deg_o[sel[r]], 1));
            }
        }
    }
}

// ---------------- bucket fill: CSR of active edges per dst ----------------
__global__ void k_bucket(const int* __restrict__ src, const int* __restrict__ dst,
                         const int* __restrict__ map, const int* __restrict__ off,
                         int* __restrict__ cursor, int* __restrict__ bucket, int n_edges) {
    int stride = gridDim.x * blockDim.x;
    int tid = blockIdx.x * blockDim.x + threadIdx.x;
    for (int e = tid; e < n_edges; e += stride) {
        int c = map[src[e]];
        if (c < 0) continue;
        int d = dst[e];
        int p = atomicAdd(&cursor[d], 1);
        bucket[off[d] + p] = c;
    }
}

// ---------------- gather: out[v] = (sum hw rows) * rsqrt(deg_i) + bias ----------------
__global__ void k_gather(const int* __restrict__ off, const int* __restrict__ cursor,
                         const int* __restrict__ deg_i, const int* __restrict__ bucket,
                         const float* __restrict__ hw, const float* __restrict__ bias,
                         float* __restrict__ out, int n_fine) {
    int gid = blockIdx.x * blockDim.x + threadIdx.x;
    int lane = gid & 63;
    int wave = gid >> 6;
    int nwaves = (gridDim.x * blockDim.x) >> 6;
    float2 b = *(const float2*)(bias + lane * 2);
    for (int v = wave; v < n_fine; v += nwaves) {
        int o = off[v];
        int n = cursor[v];
        float ax = 0.f, ay = 0.f, cx = 0.f, cy = 0.f;
        int j = 0;
        for (; j + 2 <= n; j += 2) {
            int c0 = bucket[o + j];
            int c1 = bucket[o + j + 1];
            float2 x0 = *(const float2*)(hw + (size_t)c0 * DIM + lane * 2);
            float2 x1 = *(const float2*)(hw + (size_t)c1 * DIM + lane * 2);
            ax += x0.x; ay += x0.y;
            cx += x1.x; cy += x1.y;
        }
        if (j < n) {
            int c0 = bucket[o + j];
            float2 x0 = *(const float2*)(hw + (size_t)c0 * DIM + lane * 2);
            ax += x0.x; ay += x0.y;
        }
        float s = rsqrtf((float)max(deg_i[v], 1));
        float2 r;
        r.x = (ax + cx) * s + b.x;
        r.y = (ay + cy) * s + b.y;
        *(float2*)(out + (size_t)v * DIM + lane * 2) = r;
    }
}

extern "C" void kernel_launch(void* const* d_in, const int* in_sizes, int n_in,
                              void* d_out, int out_size, void* d_ws, size_t ws_size,
                              hipStream_t stream) {
    const float* feat = (const float*)d_in[0];
    const int* src = (const int*)d_in[1];
    const int* dst = (const int*)d_in[2];
    const int* sel = (const int*)d_in[3];
    const float* W = (const float*)d_in[4];
    const float* bias = (const float*)d_in[5];
    float* out = (float*)d_out;

    int n_fine = out_size / DIM;       // 50000
    int n_coarse = in_sizes[0] / DIM;  // 25000
    int n_edges = in_sizes[1];         // 800000

    int half_words = ((n_fine + 3) / 4 + 1) & ~1;  // 12500 for n_fine=50000 (<=12512)
    int chunk = ((n_edges + NB - 1) / NB + 3) & ~3;  // multiple of 4 -> int4-aligned chunks

    // Workspace: 5 x n_fine ints + blksum, then hw (aliases partial), then bucket.
    int* deg_o = (int*)d_ws;                 // [n_fine]
    int* deg_i = deg_o + n_fine;             // [n_fine]
    int* map = deg_i + n_fine;               // [n_fine]
    int* off = map + n_fine;                 // [n_fine]
    int* cursor = off + n_fine;              // [n_fine]
    int* blksum = cursor + n_fine;           // [64]
    float* hw = (float*)(blksum + 64);       // [n_coarse*DIM] = 12.8 MB
    unsigned int* partial = (unsigned int*)hw;  // 4*NB*half_words u32 = 12.8 MB (dead before k_gemm)
    int* bucket = (int*)(hw + (size_t)n_coarse * DIM);  // [n_edges]

    int nb_scan = (n_fine + 1023) / 1024;

    hipLaunchKernelGGL(k_hist, dim3(4 * NB), dim3(HIST_T), 0, stream,
                       src, dst, partial, n_edges, half_words, chunk);
    hipLaunchKernelGGL(k_hreduce, dim3((2 * half_words + 255) / 256), dim3(256), 0, stream,
                       partial, deg_o, deg_i, map, cursor, half_words, n_fine);
    hipLaunchKernelGGL(k_map, dim3((n_coarse + 255) / 256), dim3(256), 0, stream, sel, map, n_coarse);
    hipLaunchKernelGGL(k_scan1, dim3(nb_scan), dim3(256), 0, stream, deg_i, off, blksum, n_fine);
    hipLaunchKernelGGL(k_scan2, dim3(1), dim3(64), 0, stream, blksum, nb_scan);
    hipLaunchKernelGGL(k_scan3, dim3(256), dim3(256), 0, stream, off, blksum, n_fine);
    hipLaunchKernelGGL(k_gemm, dim3(512), dim3(256), 0, stream, feat, sel, deg_o, W, hw, n_coarse);
    hipLaunchKernelGGL(k_bucket, dim3(1024), dim3(256), 0, stream, src, dst, map, off, cursor, bucket, n_edges);
    hipLaunchKernelGGL(k_gather, dim3((n_fine * 64 + 255) / 256), dim3(256), 0, stream,
                       off, cursor, deg_i, bucket, hw, bias, out, n_fine);
}

// Round 4
// 112.793 us; speedup vs baseline: 4.7151x; 1.3520x over previous
//
#include <hip/hip_runtime.h>

#define DIM 128
#define NB 64          // edge chunks per histogram
#define HIST_T 512     // threads per hist block

typedef __attribute__((ext_vector_type(8))) short bf16x8;
typedef __attribute__((ext_vector_type(4))) float f32x4;

static __device__ inline short f2bf(float f) {
    union { float f; unsigned u; } x;
    x.f = f;
    unsigned r = (x.u + 0x7FFF + ((x.u >> 16) & 1)) >> 16;  // RNE
    return (short)r;
}

// ---------------- privatized LDS histograms ----------------
__global__ __launch_bounds__(HIST_T) void k_hist(
    const int* __restrict__ src, const int* __restrict__ dst,
    unsigned int* __restrict__ partial, int n_edges, int half_words, int chunk) {
    __shared__ unsigned int hist[12512];  // 50 KB; half_words <= 12512
    int b = blockIdx.x & (NB - 1);
    int g = blockIdx.x >> 6;          // 0..3
    int r = g & 1;                    // node-range half
    const int* __restrict__ idx = (g >> 1) ? dst : src;
    int half_bins = half_words * 2;
    int lo = r * half_bins;

    for (int i = threadIdx.x; i < half_words; i += HIST_T) hist[i] = 0;
    __syncthreads();

    int e0 = b * chunk;
    int e1 = min(e0 + chunk, n_edges);
    int qs = e0 >> 2, qe = e1 >> 2;
    for (int q = qs + threadIdx.x; q < qe; q += HIST_T) {
        int4 v = ((const int4*)idx)[q];
        unsigned int t;
        t = (unsigned int)(v.x - lo);
        if (t < (unsigned int)half_bins) atomicAdd(&hist[t >> 1], 1u << ((t & 1) * 16));
        t = (unsigned int)(v.y - lo);
        if (t < (unsigned int)half_bins) atomicAdd(&hist[t >> 1], 1u << ((t & 1) * 16));
        t = (unsigned int)(v.z - lo);
        if (t < (unsigned int)half_bins) atomicAdd(&hist[t >> 1], 1u << ((t & 1) * 16));
        t = (unsigned int)(v.w - lo);
        if (t < (unsigned int)half_bins) atomicAdd(&hist[t >> 1], 1u << ((t & 1) * 16));
    }
    for (int e = (qe << 2) + threadIdx.x; e < e1; e += HIST_T) {
        unsigned int t = (unsigned int)(idx[e] - lo);
        if (t < (unsigned int)half_bins) atomicAdd(&hist[t >> 1], 1u << ((t & 1) * 16));
    }
    __syncthreads();

    unsigned int* dstp = partial + (size_t)blockIdx.x * half_words;
    for (int i = threadIdx.x; i < half_words; i += HIST_T) dstp[i] = hist[i];
}

// ---------------- reduce partials -> deg_o, deg_i; init map=-1, cursor=0 ----------------
__global__ void k_hreduce(const unsigned int* __restrict__ partial,
                          int* __restrict__ deg_o, int* __restrict__ deg_i,
                          int* __restrict__ map, int* __restrict__ cursor,
                          int half_words, int n_fine) {
    int w = blockIdx.x * blockDim.x + threadIdx.x;
    int words = half_words * 2;
    if (w >= words) return;
    int r = (w >= half_words) ? 1 : 0;
    int wl = w - r * half_words;
    unsigned int s0 = 0, s1 = 0;
    const unsigned int* p0 = partial + (size_t)(r * NB) * half_words + wl;        // src
    const unsigned int* p1 = partial + (size_t)((2 + r) * NB) * half_words + wl;  // dst
    for (int b = 0; b < NB; ++b) {
        s0 += p0[(size_t)b * half_words];
        s1 += p1[(size_t)b * half_words];
    }
    int i0 = 2 * w, i1 = 2 * w + 1;
    if (i0 < n_fine) {
        deg_o[i0] = (int)(s0 & 0xFFFF);
        deg_i[i0] = (int)(s1 & 0xFFFF);
        map[i0] = -1;
        cursor[i0] = 0;
    }
    if (i1 < n_fine) {
        deg_o[i1] = (int)(s0 >> 16);
        deg_i[i1] = (int)(s1 >> 16);
        map[i1] = -1;
        cursor[i1] = 0;
    }
}

// ---------------- map[sel[i]] = i ; scl[i] = rsqrt(max(deg_o[sel[i]],1)) ----------------
__global__ void k_map(const int* __restrict__ sel, const int* __restrict__ deg_o,
                      int* __restrict__ map, float* __restrict__ scl, int n_sel) {
    int tid = blockIdx.x * blockDim.x + threadIdx.x;
    if (tid < n_sel) {
        int s = sel[tid];
        map[s] = tid;
        scl[tid] = rsqrtf((float)max(deg_o[s], 1));
    }
}

// ---------------- exclusive scan of deg_i -> off ----------------
__global__ __launch_bounds__(256) void k_scan1(const int* __restrict__ deg,
                                               int* __restrict__ off,
                                               int* __restrict__ blksum, int n) {
    __shared__ int s[256];
    int t = threadIdx.x;
    int base = blockIdx.x * 1024 + t * 4;
    int v0 = 0, v1 = 0, v2 = 0, v3 = 0;
    if (base + 3 < n) {
        int4 q = *(const int4*)(deg + base);
        v0 = q.x; v1 = q.y; v2 = q.z; v3 = q.w;
    } else {
        if (base + 0 < n) v0 = deg[base + 0];
        if (base + 1 < n) v1 = deg[base + 1];
        if (base + 2 < n) v2 = deg[base + 2];
    }
    int sum = v0 + v1 + v2 + v3;
    s[t] = sum;
    __syncthreads();
    for (int d = 1; d < 256; d <<= 1) {
        int x = (t >= d) ? s[t - d] : 0;
        __syncthreads();
        if (t >= d) s[t] += x;
        __syncthreads();
    }
    int excl = s[t] - sum;
    if (t == 255) blksum[blockIdx.x] = s[255];
    if (base + 0 < n) off[base + 0] = excl;
    if (base + 1 < n) off[base + 1] = excl + v0;
    if (base + 2 < n) off[base + 2] = excl + v0 + v1;
    if (base + 3 < n) off[base + 3] = excl + v0 + v1 + v2;
}

__global__ void k_scan2(int* __restrict__ blksum, int nb) {
    if (threadIdx.x == 0 && blockIdx.x == 0) {
        int run = 0;
        for (int b = 0; b < nb; ++b) {
            int x = blksum[b];
            blksum[b] = run;
            run += x;
        }
    }
}

__global__ void k_scan3(int* __restrict__ off, const int* __restrict__ blksum, int n) {
    int stride = gridDim.x * blockDim.x;
    int tid = blockIdx.x * blockDim.x + threadIdx.x;
    for (int i = tid; i < n; i += stride) off[i] += blksum[i >> 10];
}

// ---------------- MFMA GEMM: hw[r][c] = scl[r] * sum_k feat[r][k]*W[k][c] ----------------
// W packed to LDS in B-fragment order: group G = (kc*4+k8)*128 + n holds
// W[kc*32 + k8*8 + j][n], j=0..7, as 8 contiguous bf16 (one ds_read_b128 per MFMA).
// Each wave: 16-row x 128-col tile; A from global (f32 -> bf16 in reg).
__global__ __launch_bounds__(256) void k_gemm(
    const float* __restrict__ feat, const float* __restrict__ scl,
    const float* __restrict__ W, float* __restrict__ hw, int n_coarse) {
    __shared__ short Wl[16384];  // 32 KiB
    int t = threadIdx.x;
    for (int g = t; g < 2048; g += 256) {
        int n = g & 127;
        int kk = g >> 7;                                  // kc*4 + k8
        int kbase = ((kk >> 2) * 32) + ((kk & 3) * 8);    // k of j=0
        bf16x8 v;
#pragma unroll
        for (int j = 0; j < 8; ++j) v[j] = f2bf(W[(size_t)(kbase + j) * DIM + n]);
        *(bf16x8*)&Wl[g * 8] = v;
    }
    __syncthreads();

    int wv = t >> 6, lane = t & 63;
    int lg = lane >> 4;   // 0..3
    int lm = lane & 15;   // 0..15
    int ntiles = (n_coarse + 15) / 16;
    for (int tile = blockIdx.x * 4 + wv; tile < ntiles; tile += gridDim.x * 4) {
        int r0 = tile * 16;
        int ra = min(r0 + lm, n_coarse - 1);  // clamp A row (invalid rows not stored)
        const float* fr = feat + (size_t)ra * DIM;
        bf16x8 a[4];
#pragma unroll
        for (int kc = 0; kc < 4; ++kc) {
            float4 x0 = *(const float4*)(fr + kc * 32 + lg * 8);
            float4 x1 = *(const float4*)(fr + kc * 32 + lg * 8 + 4);
            bf16x8 av;
            av[0] = f2bf(x0.x); av[1] = f2bf(x0.y); av[2] = f2bf(x0.z); av[3] = f2bf(x0.w);
            av[4] = f2bf(x1.x); av[5] = f2bf(x1.y); av[6] = f2bf(x1.z); av[7] = f2bf(x1.w);
            a[kc] = av;
        }
        f32x4 acc[8];
#pragma unroll
        for (int cb = 0; cb < 8; ++cb) acc[cb] = (f32x4){0.f, 0.f, 0.f, 0.f};
#pragma unroll
        for (int kc = 0; kc < 4; ++kc) {
#pragma unroll
            for (int cb = 0; cb < 8; ++cb) {
                bf16x8 b = *(const bf16x8*)&Wl[(((kc * 4 + lg) * 128) + cb * 16 + lm) * 8];
                acc[cb] = __builtin_amdgcn_mfma_f32_16x16x32_bf16(a[kc], b, acc[cb], 0, 0, 0);
            }
        }
        // D: row = r0 + lg*4 + j, col = cb*16 + lm
        float sc[4];
#pragma unroll
        for (int j = 0; j < 4; ++j) {
            int r = r0 + lg * 4 + j;
            sc[j] = (r < n_coarse) ? scl[r] : 0.f;
        }
#pragma unroll
        for (int j = 0; j < 4; ++j) {
            int r = r0 + lg * 4 + j;
            if (r < n_coarse) {
                float* hr = hw + (size_t)r * DIM + lm;
#pragma unroll
                for (int cb = 0; cb < 8; ++cb) hr[cb * 16] = acc[cb][j] * sc[j];
            }
        }
    }
}

// ---------------- bucket fill: CSR of active edges per dst ----------------
__global__ void k_bucket(const int* __restrict__ src, const int* __restrict__ dst,
                         const int* __restrict__ map, const int* __restrict__ off,
                         int* __restrict__ cursor, int* __restrict__ bucket, int n_edges) {
    int stride = gridDim.x * blockDim.x;
    int tid = blockIdx.x * blockDim.x + threadIdx.x;
    for (int e = tid; e < n_edges; e += stride) {
        int c = map[src[e]];
        if (c < 0) continue;
        int d = dst[e];
        int p = atomicAdd(&cursor[d], 1);
        bucket[off[d] + p] = c;
    }
}

// ---------------- gather: out[v] = (sum hw rows) * rsqrt(deg_i) + bias ----------------
__global__ void k_gather(const int* __restrict__ off, const int* __restrict__ cursor,
                         const int* __restrict__ deg_i, const int* __restrict__ bucket,
                         const float* __restrict__ hw, const float* __restrict__ bias,
                         float* __restrict__ out, int n_fine) {
    int gid = blockIdx.x * blockDim.x + threadIdx.x;
    int lane = gid & 63;
    int wave = gid >> 6;
    int nwaves = (gridDim.x * blockDim.x) >> 6;
    float2 b = *(const float2*)(bias + lane * 2);
    for (int v = wave; v < n_fine; v += nwaves) {
        int o = off[v];
        int n = cursor[v];
        float ax = 0.f, ay = 0.f, cx = 0.f, cy = 0.f;
        int j = 0;
        for (; j + 2 <= n; j += 2) {
            int c0 = bucket[o + j];
            int c1 = bucket[o + j + 1];
            float2 x0 = *(const float2*)(hw + (size_t)c0 * DIM + lane * 2);
            float2 x1 = *(const float2*)(hw + (size_t)c1 * DIM + lane * 2);
            ax += x0.x; ay += x0.y;
            cx += x1.x; cy += x1.y;
        }
        if (j < n) {
            int c0 = bucket[o + j];
            float2 x0 = *(const float2*)(hw + (size_t)c0 * DIM + lane * 2);
            ax += x0.x; ay += x0.y;
        }
        float s = rsqrtf((float)max(deg_i[v], 1));
        float2 r;
        r.x = (ax + cx) * s + b.x;
        r.y = (ay + cy) * s + b.y;
        *(float2*)(out + (size_t)v * DIM + lane * 2) = r;
    }
}

extern "C" void kernel_launch(void* const* d_in, const int* in_sizes, int n_in,
                              void* d_out, int out_size, void* d_ws, size_t ws_size,
                              hipStream_t stream) {
    const float* feat = (const float*)d_in[0];
    const int* src = (const int*)d_in[1];
    const int* dst = (const int*)d_in[2];
    const int* sel = (const int*)d_in[3];
    const float* W = (const float*)d_in[4];
    const float* bias = (const float*)d_in[5];
    float* out = (float*)d_out;

    int n_fine = out_size / DIM;       // 50000
    int n_coarse = in_sizes[0] / DIM;  // 25000
    int n_edges = in_sizes[1];         // 800000

    int half_words = ((n_fine + 3) / 4 + 1) & ~1;    // 12500 (<=12512)
    int chunk = ((n_edges + NB - 1) / NB + 3) & ~3;  // int4-aligned chunks

    int* deg_o = (int*)d_ws;                 // [n_fine]
    int* deg_i = deg_o + n_fine;             // [n_fine]
    int* map = deg_i + n_fine;               // [n_fine]
    int* off = map + n_fine;                 // [n_fine]
    int* cursor = off + n_fine;              // [n_fine]
    int* blksum = cursor + n_fine;           // [64]
    float* hw = (float*)(blksum + 64);       // [n_coarse*DIM] = 12.8 MB
    unsigned int* partial = (unsigned int*)hw;  // aliases hw (dead before k_gemm)
    int* bucket = (int*)(hw + (size_t)n_coarse * DIM);  // [n_edges]
    float* scl = (float*)(bucket + n_edges);            // [n_coarse]

    int nb_scan = (n_fine + 1023) / 1024;
    int ntiles = (n_coarse + 15) / 16;

    hipLaunchKernelGGL(k_hist, dim3(4 * NB), dim3(HIST_T), 0, stream,
                       src, dst, partial, n_edges, half_words, chunk);
    hipLaunchKernelGGL(k_hreduce, dim3((2 * half_words + 255) / 256), dim3(256), 0, stream,
                       partial, deg_o, deg_i, map, cursor, half_words, n_fine);
    hipLaunchKernelGGL(k_map, dim3((n_coarse + 255) / 256), dim3(256), 0, stream,
                       sel, deg_o, map, scl, n_coarse);
    hipLaunchKernelGGL(k_scan1, dim3(nb_scan), dim3(256), 0, stream, deg_i, off, blksum, n_fine);
    hipLaunchKernelGGL(k_scan2, dim3(1), dim3(64), 0, stream, blksum, nb_scan);
    hipLaunchKernelGGL(k_scan3, dim3(256), dim3(256), 0, stream, off, blksum, n_fine);
    hipLaunchKernelGGL(k_gemm, dim3((ntiles + 3) / 4), dim3(256), 0, stream,
                       feat, scl, W, hw, n_coarse);
    hipLaunchKernelGGL(k_bucket, dim3(1024), dim3(256), 0, stream, src, dst, map, off, cursor, bucket, n_edges);
    hipLaunchKernelGGL(k_gather, dim3((n_fine * 64 + 255) / 256), dim3(256), 0, stream,
                       off, cursor, deg_i, bucket, hw, bias, out, n_fine);
}

// Round 6
// 110.278 us; speedup vs baseline: 4.8227x; 1.0228x over previous
//
#include <hip/hip_runtime.h>

#define DIM 128
#define NB 64          // edge chunks
#define HIST_T 512

typedef __attribute__((ext_vector_type(8))) short bf16x8;
typedef __attribute__((ext_vector_type(4))) float f32x4;

static __device__ inline short f2bf(float f) {
    union { float f; unsigned u; } x;
    x.f = f;
    unsigned r = (x.u + 0x7FFF + ((x.u >> 16) & 1)) >> 16;  // RNE
    return (short)r;
}
static __device__ inline float bflo(unsigned u) {
    union { unsigned u; float f; } x; x.u = u << 16; return x.f;
}
static __device__ inline float bfhi(unsigned u) {
    union { unsigned u; float f; } x; x.u = u & 0xFFFF0000u; return x.f;
}

// ---------------- map init / fill ----------------
__global__ void k_map1(int* __restrict__ map, int n_fine) {
    int tid = blockIdx.x * blockDim.x + threadIdx.x;
    if (tid < n_fine) map[tid] = -1;
}
__global__ void k_map2(const int* __restrict__ sel, int* __restrict__ map, int n_sel) {
    int tid = blockIdx.x * blockDim.x + threadIdx.x;
    if (tid < n_sel) map[sel[tid]] = tid;
}

// ---------------- privatized LDS histograms: 3 classes x 2 ranges x NB chunks ----------------
// cls 0: full src histogram (deg_out). cls 1: full dst histogram (deg_in).
// cls 2: ACTIVE dst histogram (edges with map[src]>=0) -> CSR layout.
// Packed 2 x u16 bins per u32 word; per-chunk counts << 65536.
__global__ __launch_bounds__(HIST_T) void k_hist(
    const int* __restrict__ src, const int* __restrict__ dst, const int* __restrict__ map,
    unsigned int* __restrict__ partial, int n_edges, int half_words, int chunk) {
    __shared__ unsigned int hist[12512];  // 50 KB
    int b = blockIdx.x & (NB - 1);
    int g = blockIdx.x / NB;   // 0..5
    int cls = g >> 1;
    int r = g & 1;
    int half_bins = half_words * 2;
    int lo = r * half_bins;

    for (int i = threadIdx.x; i < half_words; i += HIST_T) hist[i] = 0;
    __syncthreads();

    int e0 = b * chunk;
    int e1 = min(e0 + chunk, n_edges);
    int qs = e0 >> 2, qe = e1 >> 2;

#define CNT1(x)                                                                      \
    {                                                                                \
        unsigned t = (unsigned)((x) - lo);                                           \
        if (t < (unsigned)half_bins) atomicAdd(&hist[t >> 1], 1u << ((t & 1) * 16)); \
    }
#define CNTA(d, s)                                                                       \
    {                                                                                    \
        unsigned t = (unsigned)((d) - lo);                                               \
        if (t < (unsigned)half_bins && map[s] >= 0)                                      \
            atomicAdd(&hist[t >> 1], 1u << ((t & 1) * 16));                              \
    }
    if (cls == 0) {
        for (int q = qs + threadIdx.x; q < qe; q += HIST_T) {
            int4 v = ((const int4*)src)[q];
            CNT1(v.x); CNT1(v.y); CNT1(v.z); CNT1(v.w);
        }
        for (int e = (qe << 2) + threadIdx.x; e < e1; e += HIST_T) CNT1(src[e]);
    } else if (cls == 1) {
        for (int q = qs + threadIdx.x; q < qe; q += HIST_T) {
            int4 v = ((const int4*)dst)[q];
            CNT1(v.x); CNT1(v.y); CNT1(v.z); CNT1(v.w);
        }
        for (int e = (qe << 2) + threadIdx.x; e < e1; e += HIST_T) CNT1(dst[e]);
    } else {
        for (int q = qs + threadIdx.x; q < qe; q += HIST_T) {
            int4 d4 = ((const int4*)dst)[q];
            int4 s4 = ((const int4*)src)[q];
            CNTA(d4.x, s4.x); CNTA(d4.y, s4.y); CNTA(d4.z, s4.z); CNTA(d4.w, s4.w);
        }
        for (int e = (qe << 2) + threadIdx.x; e < e1; e += HIST_T) CNTA(dst[e], src[e]);
    }
#undef CNT1
#undef CNTA
    __syncthreads();

    unsigned int* dstp = partial + (size_t)blockIdx.x * half_words;
    for (int i = threadIdx.x; i < half_words; i += HIST_T) dstp[i] = hist[i];
}

// ---------------- reduce: ri, scl, deg_act; in-place chunk-prefix of active region ----------------
__global__ void k_hreduce(unsigned int* __restrict__ partial, const int* __restrict__ map,
                          float* __restrict__ ri, float* __restrict__ scl,
                          int* __restrict__ deg_act, int half_words, int n_fine) {
    int w = blockIdx.x * blockDim.x + threadIdx.x;
    int words = half_words * 2;
    if (w >= words) return;
    int r = (w >= half_words) ? 1 : 0;
    int wl = w - r * half_words;
    const unsigned* p_src = partial + (size_t)((0 + r) * NB) * half_words + wl;
    const unsigned* p_dst = partial + (size_t)((2 + r) * NB) * half_words + wl;
    unsigned* p_act = partial + (size_t)((4 + r) * NB) * half_words + wl;
    unsigned s_src = 0, s_dst = 0, run = 0;
    for (int b = 0; b < NB; ++b) {
        s_src += p_src[(size_t)b * half_words];
        s_dst += p_dst[(size_t)b * half_words];
        unsigned t = p_act[(size_t)b * half_words];
        p_act[(size_t)b * half_words] = run;  // exclusive per-chunk prefix (packed u16, no carry)
        run += t;
    }
    int i0 = 2 * w, i1 = i0 + 1;
    if (i0 < n_fine) {
        ri[i0] = rsqrtf((float)max((int)(s_dst & 0xFFFF), 1));
        deg_act[i0] = (int)(run & 0xFFFF);
        int c = map[i0];
        if (c >= 0) scl[c] = rsqrtf((float)max((int)(s_src & 0xFFFF), 1));
    }
    if (i1 < n_fine) {
        ri[i1] = rsqrtf((float)max((int)(s_dst >> 16), 1));
        deg_act[i1] = (int)(run >> 16);
        int c = map[i1];
        if (c >= 0) scl[c] = rsqrtf((float)max((int)(s_src >> 16), 1));
    }
}

// ---------------- exclusive scan of deg_act -> off ----------------
__global__ __launch_bounds__(256) void k_scan1(const int* __restrict__ deg,
                                               int* __restrict__ off,
                                               int* __restrict__ blksum, int n) {
    __shared__ int s[256];
    int t = threadIdx.x;
    int base = blockIdx.x * 1024 + t * 4;
    int v0 = 0, v1 = 0, v2 = 0, v3 = 0;
    if (base + 3 < n) {
        int4 q = *(const int4*)(deg + base);
        v0 = q.x; v1 = q.y; v2 = q.z; v3 = q.w;
    } else {
        if (base + 0 < n) v0 = deg[base + 0];
        if (base + 1 < n) v1 = deg[base + 1];
        if (base + 2 < n) v2 = deg[base + 2];
    }
    int sum = v0 + v1 + v2 + v3;
    s[t] = sum;
    __syncthreads();
    for (int d = 1; d < 256; d <<= 1) {
        int x = (t >= d) ? s[t - d] : 0;
        __syncthreads();
        if (t >= d) s[t] += x;
        __syncthreads();
    }
    int excl = s[t] - sum;
    if (t == 255) blksum[blockIdx.x] = s[255];
    if (base + 0 < n) off[base + 0] = excl;
    if (base + 1 < n) off[base + 1] = excl + v0;
    if (base + 2 < n) off[base + 2] = excl + v0 + v1;
    if (base + 3 < n) off[base + 3] = excl + v0 + v1 + v2;
}

__global__ void k_scan2(int* __restrict__ blksum, int nb) {
    if (threadIdx.x == 0 && blockIdx.x == 0) {
        int run = 0;
        for (int b = 0; b < nb; ++b) {
            int x = blksum[b];
            blksum[b] = run;
            run += x;
        }
    }
}

__global__ void k_scan3(int* __restrict__ off, const int* __restrict__ blksum, int n) {
    int stride = gridDim.x * blockDim.x;
    int tid = blockIdx.x * blockDim.x + threadIdx.x;
    for (int i = tid; i < n; i += stride) off[i] += blksum[i >> 10];
}

// ---------------- MFMA GEMM -> bf16 hw ----------------
__global__ __launch_bounds__(256) void k_gemm(
    const float* __restrict__ feat, const float* __restrict__ scl,
    const float* __restrict__ W, unsigned short* __restrict__ hwb, int n_coarse) {
    __shared__ short Wl[16384];  // 32 KiB, B-fragment order
    int t = threadIdx.x;
    for (int g = t; g < 2048; g += 256) {
        int n = g & 127;
        int kk = g >> 7;
        int kbase = ((kk >> 2) * 32) + ((kk & 3) * 8);
        bf16x8 v;
#pragma unroll
        for (int j = 0; j < 8; ++j) v[j] = f2bf(W[(size_t)(kbase + j) * DIM + n]);
        *(bf16x8*)&Wl[g * 8] = v;
    }
    __syncthreads();

    int wv = t >> 6, lane = t & 63;
    int lg = lane >> 4;
    int lm = lane & 15;
    int ntiles = (n_coarse + 15) / 16;
    for (int tile = blockIdx.x * 4 + wv; tile < ntiles; tile += gridDim.x * 4) {
        int r0 = tile * 16;
        int ra = min(r0 + lm, n_coarse - 1);
        const float* fr = feat + (size_t)ra * DIM;
        bf16x8 a[4];
#pragma unroll
        for (int kc = 0; kc < 4; ++kc) {
            float4 x0 = *(const float4*)(fr + kc * 32 + lg * 8);
            float4 x1 = *(const float4*)(fr + kc * 32 + lg * 8 + 4);
            bf16x8 av;
            av[0] = f2bf(x0.x); av[1] = f2bf(x0.y); av[2] = f2bf(x0.z); av[3] = f2bf(x0.w);
            av[4] = f2bf(x1.x); av[5] = f2bf(x1.y); av[6] = f2bf(x1.z); av[7] = f2bf(x1.w);
            a[kc] = av;
        }
        f32x4 acc[8];
#pragma unroll
        for (int cb = 0; cb < 8; ++cb) acc[cb] = (f32x4){0.f, 0.f, 0.f, 0.f};
#pragma unroll
        for (int kc = 0; kc < 4; ++kc) {
#pragma unroll
            for (int cb = 0; cb < 8; ++cb) {
                bf16x8 b = *(const bf16x8*)&Wl[(((kc * 4 + lg) * 128) + cb * 16 + lm) * 8];
                acc[cb] = __builtin_amdgcn_mfma_f32_16x16x32_bf16(a[kc], b, acc[cb], 0, 0, 0);
            }
        }
#pragma unroll
        for (int j = 0; j < 4; ++j) {
            int r = r0 + lg * 4 + j;
            if (r < n_coarse) {
                float sc = scl[r];
                unsigned short* hr = hwb + (size_t)r * DIM + lm;
#pragma unroll
                for (int cb = 0; cb < 8; ++cb)
                    hr[cb * 16] = (unsigned short)f2bf(acc[cb][j] * sc);
            }
        }
    }
}

// ---------------- bucket: LDS counting sort (no global atomics) ----------------
// Grid = 2*NB blocks: b = chunk, r = node-range half. LDS cursors seeded with the
// chunk's exclusive prefix row; rank = LDS fetch_add -> globally unique CSR slot.
__global__ __launch_bounds__(HIST_T) void k_bucket(
    const int* __restrict__ src, const int* __restrict__ dst, const int* __restrict__ map,
    const int* __restrict__ off, const unsigned int* __restrict__ partial,
    int* __restrict__ bucket, int n_edges, int half_words, int chunk) {
    __shared__ unsigned int cur[12512];
    int b = blockIdx.x >> 1;
    int r = blockIdx.x & 1;
    int half_bins = half_words * 2;
    int lo = r * half_bins;
    const unsigned* pfx = partial + (size_t)((4 + r) * NB + b) * half_words;
    for (int i = threadIdx.x; i < half_words; i += HIST_T) cur[i] = pfx[i];
    __syncthreads();

    int e0 = b * chunk;
    int e1 = min(e0 + chunk, n_edges);
    int qs = e0 >> 2, qe = e1 >> 2;
#define PROC(d, s)                                                            \
    {                                                                         \
        unsigned t = (unsigned)((d) - lo);                                    \
        if (t < (unsigned)half_bins) {                                        \
            int c = map[s];                                                   \
            if (c >= 0) {                                                     \
                int sh = (t & 1) * 16;                                        \
                unsigned old = atomicAdd(&cur[t >> 1], 1u << sh);             \
                bucket[off[d] + (int)((old >> sh) & 0xFFFF)] = c;             \
            }                                                                 \
        }                                                                     \
    }
    for (int q = qs + threadIdx.x; q < qe; q += HIST_T) {
        int4 d4 = ((const int4*)dst)[q];
        int4 s4 = ((const int4*)src)[q];
        PROC(d4.x, s4.x); PROC(d4.y, s4.y); PROC(d4.z, s4.z); PROC(d4.w, s4.w);
    }
    for (int e = (qe << 2) + threadIdx.x; e < e1; e += HIST_T) PROC(dst[e], src[e]);
#undef PROC
}

// ---------------- gather: out[v] = (sum bf16 hw rows) * ri[v] + bias ----------------
__global__ void k_gather(const int* __restrict__ off, const int* __restrict__ deg_act,
                         const float* __restrict__ ri, const int* __restrict__ bucket,
                         const unsigned int* __restrict__ hwb, const float* __restrict__ bias,
                         float* __restrict__ out, int n_fine) {
    int gid = blockIdx.x * blockDim.x + threadIdx.x;
    int lane = gid & 63;
    int wave = gid >> 6;
    int nwaves = (gridDim.x * blockDim.x) >> 6;
    float2 bb = *(const float2*)(bias + lane * 2);
    for (int v = wave; v < n_fine; v += nwaves) {
        int o = off[v];
        int n = deg_act[v];
        float ax = 0.f, ay = 0.f, cx = 0.f, cy = 0.f;
        int j = 0;
        for (; j + 2 <= n; j += 2) {
            int c0 = bucket[o + j];
            int c1 = bucket[o + j + 1];
            unsigned u0 = hwb[(size_t)c0 * (DIM / 2) + lane];
            unsigned u1 = hwb[(size_t)c1 * (DIM / 2) + lane];
            ax += bflo(u0); ay += bfhi(u0);
            cx += bflo(u1); cy += bfhi(u1);
        }
        if (j < n) {
            unsigned u0 = hwb[(size_t)bucket[o + j] * (DIM / 2) + lane];
            ax += bflo(u0); ay += bfhi(u0);
        }
        float s = ri[v];
        float2 rv;
        rv.x = (ax + cx) * s + bb.x;
        rv.y = (ay + cy) * s + bb.y;
        *(float2*)(out + (size_t)v * DIM + lane * 2) = rv;
    }
}

extern "C" void kernel_launch(void* const* d_in, const int* in_sizes, int n_in,
                              void* d_out, int out_size, void* d_ws, size_t ws_size,
                              hipStream_t stream) {
    const float* feat = (const float*)d_in[0];
    const int* src = (const int*)d_in[1];
    const int* dst = (const int*)d_in[2];
    const int* sel = (const int*)d_in[3];
    const float* W = (const float*)d_in[4];
    const float* bias = (const float*)d_in[5];
    float* out = (float*)d_out;

    int n_fine = out_size / DIM;       // 50000
    int n_coarse = in_sizes[0] / DIM;  // 25000
    int n_edges = in_sizes[1];         // 800000

    int half_words = ((n_fine + 3) / 4 + 1) & ~1;    // 12500 (<= 12512)
    int chunk = ((n_edges + NB - 1) / NB + 3) & ~3;  // int4-aligned chunks

    // Workspace
    int* map = (int*)d_ws;                      // [n_fine]
    int* off = map + n_fine;                    // [n_fine]
    int* deg_act = off + n_fine;                // [n_fine]
    float* ri = (float*)(deg_act + n_fine);     // [n_fine]
    int* blksum = (int*)(ri + n_fine);          // [64]
    float* scl = (float*)(blksum + 64);         // [n_coarse]
    unsigned short* hwb = (unsigned short*)(scl + n_coarse);  // [n_coarse*DIM] bf16
    int* bucket = (int*)(hwb + (size_t)n_coarse * DIM);       // [n_edges]
    unsigned* partial = (unsigned*)(bucket + n_edges);        // [6*NB*half_words]

    int nb_scan = (n_fine + 1023) / 1024;
    int ntiles = (n_coarse + 15) / 16;

    hipLaunchKernelGGL(k_map1, dim3((n_fine + 255) / 256), dim3(256), 0, stream, map, n_fine);
    hipLaunchKernelGGL(k_map2, dim3((n_coarse + 255) / 256), dim3(256), 0, stream, sel, map, n_coarse);
    hipLaunchKernelGGL(k_hist, dim3(6 * NB), dim3(HIST_T), 0, stream,
                       src, dst, map, partial, n_edges, half_words, chunk);
    hipLaunchKernelGGL(k_hreduce, dim3((2 * half_words + 255) / 256), dim3(256), 0, stream,
                       partial, map, ri, scl, deg_act, half_words, n_fine);
    hipLaunchKernelGGL(k_scan1, dim3(nb_scan), dim3(256), 0, stream, deg_act, off, blksum, n_fine);
    hipLaunchKernelGGL(k_scan2, dim3(1), dim3(64), 0, stream, blksum, nb_scan);
    hipLaunchKernelGGL(k_scan3, dim3(256), dim3(256), 0, stream, off, blksum, n_fine);
    hipLaunchKernelGGL(k_gemm, dim3((ntiles + 3) / 4), dim3(256), 0, stream,
                       feat, scl, W, hwb, n_coarse);
    hipLaunchKernelGGL(k_bucket, dim3(2 * NB), dim3(HIST_T), 0, stream,
                       src, dst, map, off, partial, bucket, n_edges, half_words, chunk);
    hipLaunchKernelGGL(k_gather, dim3((n_fine * 64 + 255) / 256), dim3(256), 0, stream,
                       off, deg_act, ri, bucket, (const unsigned int*)hwb, bias, out, n_fine);
}

// Round 7
// 103.999 us; speedup vs baseline: 5.1138x; 1.0604x over previous
//
#include <hip/hip_runtime.h>

#define DIM 128
#define NB 64          // edge chunks
#define QW 6272        // LDS words per quarter-range histogram (>= qw)

typedef __attribute__((ext_vector_type(8))) short bf16x8;
typedef __attribute__((ext_vector_type(4))) float f32x4;

static __device__ inline short f2bf(float f) {
    union { float f; unsigned u; } x;
    x.f = f;
    unsigned r = (x.u + 0x7FFF + ((x.u >> 16) & 1)) >> 16;  // RNE
    return (short)r;
}
static __device__ inline float bflo(unsigned u) {
    union { unsigned u; float f; } x; x.u = u << 16; return x.f;
}
static __device__ inline float bfhi(unsigned u) {
    union { unsigned u; float f; } x; x.u = u & 0xFFFF0000u; return x.f;
}

// ---------------- map init (sentinel = n_coarse -> zero row) / fill ----------------
__global__ void k_map1(int* __restrict__ map, int n_fine, int n_coarse) {
    int tid = blockIdx.x * blockDim.x + threadIdx.x;
    if (tid < n_fine) map[tid] = n_coarse;
}
__global__ void k_map2(const int* __restrict__ sel, int* __restrict__ map, int n_sel) {
    int tid = blockIdx.x * blockDim.x + threadIdx.x;
    if (tid < n_sel) map[sel[tid]] = tid;
}

// ---------------- dual LDS histogram: src + dst counted in ONE edge pass ----------------
// Grid = 4*NB blocks: b = chunk (edges), r = quarter node-range.
// Packed 2 x u16 bins per u32 word; per-chunk counts << 65536.
// partial layout: [cls][r][b][word], cls0 = src (deg_out), cls1 = dst (deg_in).
__global__ __launch_bounds__(512) void k_hist(
    const int* __restrict__ src, const int* __restrict__ dst,
    unsigned int* __restrict__ partial, int n_edges, int qw, int qbins, int chunk) {
    __shared__ unsigned int hs[QW], hd[QW];
    int b = blockIdx.x & (NB - 1);
    int r = blockIdx.x >> 6;   // 0..3
    int lo = r * qbins;

    for (int i = threadIdx.x; i < qw; i += 512) { hs[i] = 0; hd[i] = 0; }
    __syncthreads();

    int e0 = b * chunk;
    int e1 = min(e0 + chunk, n_edges);
    int qs = e0 >> 2, qe = e1 >> 2;

#define CNT(h, x)                                                                   \
    {                                                                               \
        unsigned t = (unsigned)((x) - lo);                                          \
        if (t < (unsigned)qbins) atomicAdd(&h[t >> 1], 1u << ((t & 1) * 16));       \
    }
    for (int q = qs + threadIdx.x; q < qe; q += 512) {
        int4 s4 = ((const int4*)src)[q];
        int4 d4 = ((const int4*)dst)[q];
        CNT(hs, s4.x); CNT(hs, s4.y); CNT(hs, s4.z); CNT(hs, s4.w);
        CNT(hd, d4.x); CNT(hd, d4.y); CNT(hd, d4.z); CNT(hd, d4.w);
    }
    for (int e = (qe << 2) + threadIdx.x; e < e1; e += 512) {
        CNT(hs, src[e]);
        CNT(hd, dst[e]);
    }
#undef CNT
    __syncthreads();

    unsigned int* ps = partial + ((size_t)(0 * 4 + r) * NB + b) * qw;
    unsigned int* pd = partial + ((size_t)(1 * 4 + r) * NB + b) * qw;
    for (int i = threadIdx.x; i < qw; i += 512) { ps[i] = hs[i]; pd[i] = hd[i]; }
}

// ---------------- reduce: deg(=deg_in), ri, scl; in-place chunk-prefix of cls1 ----------------
__global__ void k_hreduce(unsigned int* __restrict__ partial, const int* __restrict__ map,
                          float* __restrict__ ri, float* __restrict__ scl,
                          int* __restrict__ deg, int qw, int qbins, int n_fine, int n_coarse) {
    int w = blockIdx.x * blockDim.x + threadIdx.x;
    if (w >= 4 * qw) return;
    int r = w / qw;
    int wl = w - r * qw;
    const unsigned* p_src = partial + ((size_t)(0 * 4 + r) * NB) * qw + wl;
    unsigned* p_dst = partial + ((size_t)(1 * 4 + r) * NB) * qw + wl;
    unsigned s_src = 0, run = 0;
    for (int b = 0; b < NB; ++b) {
        s_src += p_src[(size_t)b * qw];
        unsigned t = p_dst[(size_t)b * qw];
        p_dst[(size_t)b * qw] = run;  // exclusive per-chunk prefix (packed u16, no carry)
        run += t;
    }
    int i0 = r * qbins + 2 * wl, i1 = i0 + 1;
    if (i0 < n_fine) {
        int d = (int)(run & 0xFFFF);
        deg[i0] = d;
        ri[i0] = rsqrtf((float)max(d, 1));
        int c = map[i0];
        if (c < n_coarse) scl[c] = rsqrtf((float)max((int)(s_src & 0xFFFF), 1));
    }
    if (i1 < n_fine) {
        int d = (int)(run >> 16);
        deg[i1] = d;
        ri[i1] = rsqrtf((float)max(d, 1));
        int c = map[i1];
        if (c < n_coarse) scl[c] = rsqrtf((float)max((int)(s_src >> 16), 1));
    }
}

// ---------------- exclusive scan of deg -> off0 (per-1024-block) + blksum ----------------
__global__ __launch_bounds__(256) void k_scan1(const int* __restrict__ deg,
                                               int* __restrict__ off0,
                                               int* __restrict__ blksum, int n) {
    __shared__ int s[256];
    int t = threadIdx.x;
    int base = blockIdx.x * 1024 + t * 4;
    int v0 = 0, v1 = 0, v2 = 0, v3 = 0;
    if (base + 3 < n) {
        int4 q = *(const int4*)(deg + base);
        v0 = q.x; v1 = q.y; v2 = q.z; v3 = q.w;
    } else {
        if (base + 0 < n) v0 = deg[base + 0];
        if (base + 1 < n) v1 = deg[base + 1];
        if (base + 2 < n) v2 = deg[base + 2];
    }
    int sum = v0 + v1 + v2 + v3;
    s[t] = sum;
    __syncthreads();
    for (int d = 1; d < 256; d <<= 1) {
        int x = (t >= d) ? s[t - d] : 0;
        __syncthreads();
        if (t >= d) s[t] += x;
        __syncthreads();
    }
    int excl = s[t] - sum;
    if (t == 255) blksum[blockIdx.x] = s[255];
    if (base + 0 < n) off0[base + 0] = excl;
    if (base + 1 < n) off0[base + 1] = excl + v0;
    if (base + 2 < n) off0[base + 2] = excl + v0 + v1;
    if (base + 3 < n) off0[base + 3] = excl + v0 + v1 + v2;
}

__global__ void k_scan2(int* __restrict__ blksum, int nb) {
    if (threadIdx.x == 0 && blockIdx.x == 0) {
        int run = 0;
        for (int b = 0; b < nb; ++b) {
            int x = blksum[b];
            blksum[b] = run;
            run += x;
        }
    }
}

// ---------------- MFMA GEMM -> bf16 hw (+ zero row at n_coarse) ----------------
__global__ __launch_bounds__(256) void k_gemm(
    const float* __restrict__ feat, const float* __restrict__ scl,
    const float* __restrict__ W, unsigned short* __restrict__ hwb, int n_coarse) {
    __shared__ short Wl[16384];  // 32 KiB, B-fragment order
    int t = threadIdx.x;
    if (blockIdx.x == 0 && t < DIM) hwb[(size_t)n_coarse * DIM + t] = 0;  // zero row
    for (int g = t; g < 2048; g += 256) {
        int n = g & 127;
        int kk = g >> 7;
        int kbase = ((kk >> 2) * 32) + ((kk & 3) * 8);
        bf16x8 v;
#pragma unroll
        for (int j = 0; j < 8; ++j) v[j] = f2bf(W[(size_t)(kbase + j) * DIM + n]);
        *(bf16x8*)&Wl[g * 8] = v;
    }
    __syncthreads();

    int wv = t >> 6, lane = t & 63;
    int lg = lane >> 4;
    int lm = lane & 15;
    int ntiles = (n_coarse + 15) / 16;
    for (int tile = blockIdx.x * 4 + wv; tile < ntiles; tile += gridDim.x * 4) {
        int r0 = tile * 16;
        int ra = min(r0 + lm, n_coarse - 1);
        const float* fr = feat + (size_t)ra * DIM;
        bf16x8 a[4];
#pragma unroll
        for (int kc = 0; kc < 4; ++kc) {
            float4 x0 = *(const float4*)(fr + kc * 32 + lg * 8);
            float4 x1 = *(const float4*)(fr + kc * 32 + lg * 8 + 4);
            bf16x8 av;
            av[0] = f2bf(x0.x); av[1] = f2bf(x0.y); av[2] = f2bf(x0.z); av[3] = f2bf(x0.w);
            av[4] = f2bf(x1.x); av[5] = f2bf(x1.y); av[6] = f2bf(x1.z); av[7] = f2bf(x1.w);
            a[kc] = av;
        }
        f32x4 acc[8];
#pragma unroll
        for (int cb = 0; cb < 8; ++cb) acc[cb] = (f32x4){0.f, 0.f, 0.f, 0.f};
#pragma unroll
        for (int kc = 0; kc < 4; ++kc) {
#pragma unroll
            for (int cb = 0; cb < 8; ++cb) {
                bf16x8 b = *(const bf16x8*)&Wl[(((kc * 4 + lg) * 128) + cb * 16 + lm) * 8];
                acc[cb] = __builtin_amdgcn_mfma_f32_16x16x32_bf16(a[kc], b, acc[cb], 0, 0, 0);
            }
        }
#pragma unroll
        for (int j = 0; j < 4; ++j) {
            int r = r0 + lg * 4 + j;
            if (r < n_coarse) {
                float sc = scl[r];
                unsigned short* hr = hwb + (size_t)r * DIM + lm;
#pragma unroll
                for (int cb = 0; cb < 8; ++cb)
                    hr[cb * 16] = (unsigned short)f2bf(acc[cb][j] * sc);
            }
        }
    }
}

// ---------------- bucket: LDS counting sort over FULL deg_in CSR ----------------
// Grid = 4*NB blocks: b = chunk, r = quarter range. Stores map[src] (n_coarse if
// unselected -> zero row). Rank = chunk-prefix seed + LDS fetch_add.
__global__ __launch_bounds__(512) void k_bucket(
    const int* __restrict__ src, const int* __restrict__ dst, const int* __restrict__ map,
    const int* __restrict__ off0, const int* __restrict__ blksum,
    const unsigned int* __restrict__ partial,
    int* __restrict__ bucket, int n_edges, int qw, int qbins, int chunk) {
    __shared__ unsigned int cur[QW];
    int b = blockIdx.x & (NB - 1);
    int r = blockIdx.x >> 6;
    int lo = r * qbins;
    const unsigned* pfx = partial + ((size_t)(4 + r) * NB + b) * qw;  // prefixed cls1
    for (int i = threadIdx.x; i < qw; i += 512) cur[i] = pfx[i];
    __syncthreads();

    int e0 = b * chunk;
    int e1 = min(e0 + chunk, n_edges);
    int qs = e0 >> 2, qe = e1 >> 2;
#define PROC(d, s)                                                            \
    {                                                                         \
        unsigned t = (unsigned)((d) - lo);                                    \
        if (t < (unsigned)qbins) {                                            \
            int sh = (t & 1) * 16;                                            \
            unsigned old = atomicAdd(&cur[t >> 1], 1u << sh);                 \
            bucket[off0[d] + blksum[(d) >> 10] + (int)((old >> sh) & 0xFFFF)] \
                = map[s];                                                     \
        }                                                                     \
    }
    for (int q = qs + threadIdx.x; q < qe; q += 512) {
        int4 d4 = ((const int4*)dst)[q];
        int4 s4 = ((const int4*)src)[q];
        PROC(d4.x, s4.x); PROC(d4.y, s4.y); PROC(d4.z, s4.z); PROC(d4.w, s4.w);
    }
    for (int e = (qe << 2) + threadIdx.x; e < e1; e += 512) PROC(dst[e], src[e]);
#undef PROC
}

// ---------------- gather: out[v] = (sum bf16 hw rows) * ri[v] + bias (branch-free) ----------------
__global__ void k_gather(const int* __restrict__ off0, const int* __restrict__ blksum,
                         const int* __restrict__ deg, const float* __restrict__ ri,
                         const int* __restrict__ bucket, const unsigned int* __restrict__ hwb,
                         const float* __restrict__ bias, float* __restrict__ out, int n_fine) {
    int gid = blockIdx.x * blockDim.x + threadIdx.x;
    int lane = gid & 63;
    int wave = gid >> 6;
    int nwaves = (gridDim.x * blockDim.x) >> 6;
    float2 bb = *(const float2*)(bias + lane * 2);
    for (int v = wave; v < n_fine; v += nwaves) {
        int o = off0[v] + blksum[v >> 10];
        int n = deg[v];
        float ax = 0.f, ay = 0.f, cx = 0.f, cy = 0.f;
        int j = 0;
        for (; j + 4 <= n; j += 4) {
            int c0 = bucket[o + j + 0];
            int c1 = bucket[o + j + 1];
            int c2 = bucket[o + j + 2];
            int c3 = bucket[o + j + 3];
            unsigned u0 = hwb[(size_t)c0 * (DIM / 2) + lane];
            unsigned u1 = hwb[(size_t)c1 * (DIM / 2) + lane];
            unsigned u2 = hwb[(size_t)c2 * (DIM / 2) + lane];
            unsigned u3 = hwb[(size_t)c3 * (DIM / 2) + lane];
            ax += bflo(u0); ay += bfhi(u0);
            cx += bflo(u1); cy += bfhi(u1);
            ax += bflo(u2); ay += bfhi(u2);
            cx += bflo(u3); cy += bfhi(u3);
        }
        for (; j < n; ++j) {
            unsigned u0 = hwb[(size_t)bucket[o + j] * (DIM / 2) + lane];
            ax += bflo(u0); ay += bfhi(u0);
        }
        float s = ri[v];
        float2 rv;
        rv.x = (ax + cx) * s + bb.x;
        rv.y = (ay + cy) * s + bb.y;
        *(float2*)(out + (size_t)v * DIM + lane * 2) = rv;
    }
}

extern "C" void kernel_launch(void* const* d_in, const int* in_sizes, int n_in,
                              void* d_out, int out_size, void* d_ws, size_t ws_size,
                              hipStream_t stream) {
    const float* feat = (const float*)d_in[0];
    const int* src = (const int*)d_in[1];
    const int* dst = (const int*)d_in[2];
    const int* sel = (const int*)d_in[3];
    const float* W = (const float*)d_in[4];
    const float* bias = (const float*)d_in[5];
    float* out = (float*)d_out;

    int n_fine = out_size / DIM;       // 50000
    int n_coarse = in_sizes[0] / DIM;  // 25000
    int n_edges = in_sizes[1];         // 800000

    int qbins = ((n_fine + 7) / 8) * 2;              // 12500 (even); 4*qbins >= n_fine
    int qw = qbins / 2;                              // 6250 (<= QW)
    int chunk = ((n_edges + NB - 1) / NB + 3) & ~3;  // int4-aligned chunks

    // Workspace
    int* map = (int*)d_ws;                      // [n_fine]
    int* off0 = map + n_fine;                   // [n_fine]
    int* deg = off0 + n_fine;                   // [n_fine]
    float* ri = (float*)(deg + n_fine);         // [n_fine]
    int* blksum = (int*)(ri + n_fine);          // [64]
    float* scl = (float*)(blksum + 64);         // [n_coarse]
    unsigned short* hwb = (unsigned short*)(scl + n_coarse);  // [(n_coarse+1)*DIM] bf16
    int* bucket = (int*)(hwb + (size_t)(n_coarse + 1) * DIM); // [n_edges]
    unsigned* partial = (unsigned*)(bucket + n_edges);        // [2*4*NB*qw]

    int nb_scan = (n_fine + 1023) / 1024;  // 49
    int ntiles = (n_coarse + 15) / 16;

    hipLaunchKernelGGL(k_map1, dim3((n_fine + 255) / 256), dim3(256), 0, stream,
                       map, n_fine, n_coarse);
    hipLaunchKernelGGL(k_map2, dim3((n_coarse + 255) / 256), dim3(256), 0, stream,
                       sel, map, n_coarse);
    hipLaunchKernelGGL(k_hist, dim3(4 * NB), dim3(512), 0, stream,
                       src, dst, partial, n_edges, qw, qbins, chunk);
    hipLaunchKernelGGL(k_hreduce, dim3((4 * qw + 255) / 256), dim3(256), 0, stream,
                       partial, map, ri, scl, deg, qw, qbins, n_fine, n_coarse);
    hipLaunchKernelGGL(k_scan1, dim3(nb_scan), dim3(256), 0, stream, deg, off0, blksum, n_fine);
    hipLaunchKernelGGL(k_scan2, dim3(1), dim3(64), 0, stream, blksum, nb_scan);
    hipLaunchKernelGGL(k_gemm, dim3((ntiles + 3) / 4), dim3(256), 0, stream,
                       feat, scl, W, hwb, n_coarse);
    hipLaunchKernelGGL(k_bucket, dim3(4 * NB), dim3(512), 0, stream,
                       src, dst, map, off0, blksum, partial, bucket, n_edges, qw, qbins, chunk);
    hipLaunchKernelGGL(k_gather, dim3((n_fine * 64 + 255) / 256), dim3(256), 0, stream,
                       off0, blksum, deg, ri, bucket, (const unsigned int*)hwb, bias, out, n_fine);
}